// Round 8
// baseline (112.397 us; speedup 1.0000x reference)
//
#include <hip/hip_runtime.h>
#include <math.h>

#define N_   64
#define C_   256
#define S_   16
#define HW_  3136      // 56*56
#define HW4_ 784       // f32x4 per row; 784 = 12*64 + 16
#define ROWS_ (N_ * C_)        // 16384 (n,c) rows
#define BLK_  4096             // wave-per-row: 4 rows per 256-thread block

typedef float f32x4 __attribute__((ext_vector_type(4)));

__device__ __forceinline__ float sigmoidf_(float v) {
    return 1.0f / (1.0f + expf(-v));
}

// Kernel 1: global average pool, wave-per-row (unchanged from round 7).
__global__ __launch_bounds__(256) void se_pool(const float* __restrict__ x,
                                               float* __restrict__ s) {
    const int wave = threadIdx.x >> 6;
    const int lane = threadIdx.x & 63;
    const int row  = blockIdx.x * 4 + wave;      // n*C + c
    const f32x4* xr = reinterpret_cast<const f32x4*>(x + (size_t)row * HW_);

    f32x4 acc = {0.f, 0.f, 0.f, 0.f};
    #pragma unroll
    for (int u = 0; u < 12; ++u) acc += xr[lane + 64 * u];
    float sum = (acc.x + acc.y) + (acc.z + acc.w);
    if (lane < 16) {
        f32x4 v = xr[768 + lane];
        sum += (v.x + v.y) + (v.z + v.w);
    }
    #pragma unroll
    for (int off = 32; off; off >>= 1) sum += __shfl_down(sum, off, 64);
    if (lane == 0) s[row] = sum * (1.0f / (float)HW_);
}

// Kernel 2: fused gate + scale, wave-per-row, ZERO barriers.
// Each wave: (1) issues its 12+tail x row loads (HBM latency starts now),
// (2) computes g[n,c] redundantly from s/w1/w2 (L1/L2-hot) via
//     4-lanes-per-hidden-unit dots + shuffle reduces while x loads fly,
// (3) multiplies and nt-stores (nt keeps x L3-resident for other blocks).
__global__ __launch_bounds__(256) void se_gate_scale(
    const float* __restrict__ x, const float* __restrict__ s,
    const float* __restrict__ w1, const float* __restrict__ b1,
    const float* __restrict__ w2, const float* __restrict__ b2,
    float* __restrict__ out)
{
    const int wave = threadIdx.x >> 6;
    const int lane = threadIdx.x & 63;
    const int row  = blockIdx.x * 4 + wave;      // n*C + c
    const int n    = row >> 8;
    const int c    = row & (C_ - 1);
    const f32x4* xr = reinterpret_cast<const f32x4*>(x + (size_t)row * HW_);

    // (1) issue x loads first — stores depend on them anyway.
    f32x4 xv[12];
    #pragma unroll
    for (int u = 0; u < 12; ++u) xv[u] = xr[lane + 64 * u];
    f32x4 xt = {0.f, 0.f, 0.f, 0.f};
    if (lane < 16) xt = xr[768 + lane];

    // (2) gate math overlapped with the in-flight x loads.
    // h[j] = swish(b1[j] + s[n,:]·w1[j,:]): lane = 4*j + seg,
    // each lane dots a 64-element segment.
    const int j   = lane >> 2;
    const int seg = lane & 3;
    const f32x4* s4 = reinterpret_cast<const f32x4*>(s  + n * C_ + seg * 64);
    const f32x4* w4 = reinterpret_cast<const f32x4*>(w1 + j * C_ + seg * 64);
    f32x4 pa = {0.f, 0.f, 0.f, 0.f};
    #pragma unroll
    for (int m = 0; m < 16; ++m) pa += s4[m] * w4[m];
    float p = (pa.x + pa.y) + (pa.z + pa.w);
    p += __shfl_xor(p, 1, 64);
    p += __shfl_xor(p, 2, 64);                   // lanes 4j..4j+3: full dot
    float hv = p + b1[j];
    hv = hv * sigmoidf_(hv);                     // swish, replicated in group

    // g[n,c] = sigmoid(b2[c] + sum_j h[j]*w2[c,j]): seg==0 lanes carry terms.
    float term = (seg == 0) ? hv * w2[c * S_ + j] : 0.f;
    term += __shfl_xor(term, 4,  64);
    term += __shfl_xor(term, 8,  64);
    term += __shfl_xor(term, 16, 64);
    term += __shfl_xor(term, 32, 64);            // lane 0 now has full sum
    const float gv = sigmoidf_(__shfl(term, 0, 64) + b2[c]);

    // (3) scale + nt-store.
    f32x4* orow = reinterpret_cast<f32x4*>(out + (size_t)row * HW_);
    #pragma unroll
    for (int u = 0; u < 12; ++u) {
        f32x4 v = xv[u] * gv;
        __builtin_nontemporal_store(v, &orow[lane + 64 * u]);
    }
    if (lane < 16) {
        f32x4 v = xt * gv;
        __builtin_nontemporal_store(v, &orow[768 + lane]);
    }
}

extern "C" void kernel_launch(void* const* d_in, const int* in_sizes, int n_in,
                              void* d_out, int out_size, void* d_ws, size_t ws_size,
                              hipStream_t stream) {
    const float* x  = (const float*)d_in[0];
    const float* w1 = (const float*)d_in[1];
    const float* b1 = (const float*)d_in[2];
    const float* w2 = (const float*)d_in[3];
    const float* b2 = (const float*)d_in[4];
    float* out = (float*)d_out;

    float* s = (float*)d_ws;          // ROWS_ floats

    se_pool      <<<BLK_, 256, 0, stream>>>(x, s);
    se_gate_scale<<<BLK_, 256, 0, stream>>>(x, s, w1, b1, w2, b2, out);
}